// Round 3
// baseline (487.322 us; speedup 1.0000x reference)
//
#include <hip/hip_runtime.h>
#include <hip/hip_bf16.h>
#include <math.h>

// ---------------- problem constants (fixed by setup_inputs) ----------------
#define BS      2
#define NQ      11253           // 92*92 + 46*46 + 23*23 + 12*12
#define MROWS   (BS * NQ)       // 22506
#define ED      256
#define HEADS   8
#define HD      32
#define LEVELS  4
#define POINTS  4

// ---------------- fp32 tiled GEMM: C = A(MxK) @ B(KxN) + bias (+res) -------
// BM=128 x BN=64 tile, 256 threads, 8x4 acc/thread (1.33 FLOP per LDS byte).
// N in {128,256}, K=256. Only M needs a tail guard.
#define BM 128
#define BN 64
#define BK 16

__global__ __launch_bounds__(256) void gemm_bias_kernel(
    const float* __restrict__ A,     // M x K, row-major
    const float* __restrict__ B,     // K x N, row-major
    const float* __restrict__ bias,  // N
    const float* __restrict__ res,   // M x N or nullptr (residual add)
    float* __restrict__ C,           // M x N
    int M, int N, int K)
{
    __shared__ float As[BK][BM];   // transposed tile: As[k][m]
    __shared__ float Bsh[BK][BN];

    const int tid = threadIdx.x;
    const int row0 = blockIdx.x * BM;
    const int col0 = blockIdx.y * BN;
    const int tx = tid & 15;        // 0..15 -> cols tx*4
    const int ty = tid >> 4;        // 0..15 -> rows ty*8

    // B-tile load coords: 16x64 = 1024 floats = 1 float4/thread
    const int b_k = (tid * 4) >> 6;       // 0..15
    const int b_n = (tid * 4) & 63;       // 0..60 step 4

    float acc[8][4] = {};

    for (int k0 = 0; k0 < K; k0 += BK) {
        // A tile: 128x16 = 2048 floats = 2 float4/thread, scatter to As[k][m]
        #pragma unroll
        for (int half = 0; half < 2; ++half) {
            const int e   = tid * 4 + half * 1024;
            const int a_m = e >> 4;           // 0..127
            const int a_k = e & 15;           // 0,4,8,12
            const int r   = row0 + a_m;
            float4 av = make_float4(0.f, 0.f, 0.f, 0.f);
            if (r < M) av = *(const float4*)&A[(size_t)r * K + k0 + a_k];
            As[a_k + 0][a_m] = av.x;
            As[a_k + 1][a_m] = av.y;
            As[a_k + 2][a_m] = av.z;
            As[a_k + 3][a_m] = av.w;
        }
        *(float4*)&Bsh[b_k][b_n] =
            *(const float4*)&B[(size_t)(k0 + b_k) * N + col0 + b_n];
        __syncthreads();

        #pragma unroll
        for (int k = 0; k < BK; ++k) {
            const float4 a0 = *(const float4*)&As[k][ty * 8];
            const float4 a1 = *(const float4*)&As[k][ty * 8 + 4];
            const float4 b4 = *(const float4*)&Bsh[k][tx * 4];
            const float a[8] = {a0.x, a0.y, a0.z, a0.w, a1.x, a1.y, a1.z, a1.w};
            const float b[4] = {b4.x, b4.y, b4.z, b4.w};
            #pragma unroll
            for (int i = 0; i < 8; ++i)
                #pragma unroll
                for (int j = 0; j < 4; ++j)
                    acc[i][j] = fmaf(a[i], b[j], acc[i][j]);
        }
        __syncthreads();
    }

    const int cidx = col0 + tx * 4;
    const float4 bi = *(const float4*)&bias[cidx];
    #pragma unroll
    for (int i = 0; i < 8; ++i) {
        const int r = row0 + ty * 8 + i;
        if (r < M) {
            float4 vout = make_float4(acc[i][0] + bi.x, acc[i][1] + bi.y,
                                      acc[i][2] + bi.z, acc[i][3] + bi.w);
            if (res) {
                const float4 rv = *(const float4*)&res[(size_t)r * N + cidx];
                vout.x += rv.x; vout.y += rv.y; vout.z += rv.z; vout.w += rv.w;
            }
            *(float4*)&C[(size_t)r * N + cidx] = vout;
        }
    }
}

// ---------------- MSDA sampling: softmax + bilinear gather -----------------
// One block (256 thr) per (b,q); 32 lanes per head = 32 channels = one
// 128B cache line per gather corner.
__global__ __launch_bounds__(256) void msda_sample_kernel(
    const float* __restrict__ v,       // [BS][NQ][HEADS][HD]
    const float* __restrict__ offs,    // [BS][NQ][HEADS][LEVELS][POINTS][2]
    const float* __restrict__ logits,  // [BS][NQ][HEADS][16]
    const float* __restrict__ refp,    // [BS][NQ][LEVELS][2]
    float* __restrict__ out)           // [BS][NQ][HEADS][HD]
{
    const int bq  = blockIdx.x;            // b*NQ + q
    const int tid = threadIdx.x;
    const int h   = tid >> 5;              // head
    const int c   = tid & 31;              // channel within head

    __shared__ float s_off[HEADS * LEVELS * POINTS * 2]; // 256
    __shared__ float s_log[HEADS * LEVELS * POINTS];     // 128
    __shared__ float s_ref[LEVELS * 2];                  // 8

    const size_t base = (size_t)bq;
    s_off[tid] = offs[base * 256 + tid];
    if (tid < 128) s_log[tid] = logits[base * 128 + tid];
    if (tid < 8)   s_ref[tid] = refp[base * 8 + tid];
    __syncthreads();

    // per-head softmax over 16 (redundant across the 32 lanes of the head)
    float w[16];
    float mx = -1e30f;
    #pragma unroll
    for (int p = 0; p < 16; ++p) { w[p] = s_log[h * 16 + p]; mx = fmaxf(mx, w[p]); }
    float sum = 0.f;
    #pragma unroll
    for (int p = 0; p < 16; ++p) { w[p] = expf(w[p] - mx); sum += w[p]; }
    const float inv = 1.f / sum;

    const int b = bq / NQ;
    const float* vb = v + (size_t)b * NQ * ED;

    const int Wl[4] = {92, 46, 23, 12};
    const int Hl[4] = {92, 46, 23, 12};
    const int st[4] = {0, 8464, 10580, 11109};

    float acc = 0.f;
    #pragma unroll
    for (int lvl = 0; lvl < LEVELS; ++lvl) {
        const int Wd = Wl[lvl], Hd = Hl[lvl], s0 = st[lvl];
        const float rx = s_ref[lvl * 2 + 0];
        const float ry = s_ref[lvl * 2 + 1];
        #pragma unroll
        for (int pt = 0; pt < POINTS; ++pt) {
            const int oi = ((h * LEVELS + lvl) * POINTS + pt) * 2;
            // x = loc_x*W - 0.5 = ref_x*W + off_x - 0.5  (norm cancels)
            const float x = rx * (float)Wd + s_off[oi]     - 0.5f;
            const float y = ry * (float)Hd + s_off[oi + 1] - 0.5f;
            const float x0f = floorf(x), y0f = floorf(y);
            const int   x0 = (int)x0f,  y0 = (int)y0f;
            const float wx1 = x - x0f, wy1 = y - y0f;
            const float wx0 = 1.f - wx1, wy0 = 1.f - wy1;

            const bool vx0 = (x0 >= 0)     && (x0 < Wd);
            const bool vx1 = (x0 + 1 >= 0) && (x0 + 1 < Wd);
            const bool vy0 = (y0 >= 0)     && (y0 < Hd);
            const bool vy1 = (y0 + 1 >= 0) && (y0 + 1 < Hd);

            float sval = 0.f;
            if (vy0) {
                const float* rowp = vb + ((size_t)(s0 + y0 * Wd)) * ED + h * HD + c;
                if (vx0) sval += wx0 * wy0 * rowp[(size_t)x0 * ED];
                if (vx1) sval += wx1 * wy0 * rowp[(size_t)(x0 + 1) * ED];
            }
            if (vy1) {
                const float* rowp = vb + ((size_t)(s0 + (y0 + 1) * Wd)) * ED + h * HD + c;
                if (vx0) sval += wx0 * wy1 * rowp[(size_t)x0 * ED];
                if (vx1) sval += wx1 * wy1 * rowp[(size_t)(x0 + 1) * ED];
            }
            acc = fmaf(w[lvl * POINTS + pt], sval, acc);
        }
    }
    out[base * ED + tid] = acc * inv;
}

// ---------------------------------------------------------------------------
extern "C" void kernel_launch(void* const* d_in, const int* in_sizes, int n_in,
                              void* d_out, int out_size, void* d_ws, size_t ws_size,
                              hipStream_t stream) {
    const float* query = (const float*)d_in[0];   // [BS][NQ][ED]
    const float* value = (const float*)d_in[1];   // [BS][NQ][ED]
    const float* refp  = (const float*)d_in[2];   // [BS][NQ][LEVELS][2]
    // d_in[3] = spatial_shapes (constants, hardcoded)
    const float* W_val  = (const float*)d_in[4];
    const float* b_val  = (const float*)d_in[5];
    const float* W_off  = (const float*)d_in[6];
    const float* b_off  = (const float*)d_in[7];
    const float* W_attn = (const float*)d_in[8];
    const float* b_attn = (const float*)d_in[9];
    const float* W_out  = (const float*)d_in[10];
    const float* b_out  = (const float*)d_in[11];
    float* out = (float*)d_out;

    // workspace carve-up (floats)
    float* ws      = (float*)d_ws;
    float* v_ws    = ws;                                   // MROWS*256
    float* off_ws  = v_ws   + (size_t)MROWS * 256;         // MROWS*256
    float* attn_ws = off_ws + (size_t)MROWS * 256;         // MROWS*128
    float* msda_ws = attn_ws + (size_t)MROWS * 128;        // MROWS*256

    const int M = MROWS, K = ED;
    dim3 blk(256);
    dim3 grid_v((M + BM - 1) / BM, 256 / BN);  // N=256
    dim3 grid_a((M + BM - 1) / BM, 128 / BN);  // N=128

    // 1. v = value @ W_val + b_val
    hipLaunchKernelGGL(gemm_bias_kernel, grid_v, blk, 0, stream,
                       value, W_val, b_val, nullptr, v_ws, M, 256, K);
    // 2. offsets = query @ W_off + b_off
    hipLaunchKernelGGL(gemm_bias_kernel, grid_v, blk, 0, stream,
                       query, W_off, b_off, nullptr, off_ws, M, 256, K);
    // 3. attn logits = query @ W_attn + b_attn
    hipLaunchKernelGGL(gemm_bias_kernel, grid_a, blk, 0, stream,
                       query, W_attn, b_attn, nullptr, attn_ws, M, 128, K);
    // 4. softmax + bilinear sampling + attention-weighted sum
    hipLaunchKernelGGL(msda_sample_kernel, dim3(MROWS), blk, 0, stream,
                       v_ws, off_ws, attn_ws, refp, msda_ws);
    // 5. out = msda @ W_out + b_out + query (residual)
    hipLaunchKernelGGL(gemm_bias_kernel, grid_v, blk, 0, stream,
                       msda_ws, W_out, b_out, query, out, M, 256, K);
}

// Round 6
// 374.940 us; speedup vs baseline: 1.2997x; 1.2997x over previous
//
#include <hip/hip_runtime.h>
#include <hip/hip_bf16.h>
#include <math.h>

// ---------------- problem constants (fixed by setup_inputs) ----------------
#define BS      2
#define NQ      11253           // 92*92 + 46*46 + 23*23 + 12*12
#define MROWS   (BS * NQ)       // 22506
#define ED      256
#define HEADS   8
#define HD      32
#define LEVELS  4
#define POINTS  4

typedef __attribute__((ext_vector_type(8))) short  bf16x8_t;
typedef __attribute__((ext_vector_type(4))) float  f32x4_t;

__device__ __forceinline__ unsigned short f2bf(float f) {
    unsigned int u = __float_as_uint(f);
    u += 0x7FFFu + ((u >> 16) & 1u);          // round-to-nearest-even
    return (unsigned short)(u >> 16);
}
__device__ __forceinline__ float bf2f(unsigned short h) {
    return __uint_as_float(((unsigned int)h) << 16);
}

// ---------------- weight prep: W[K][N] fp32 -> W^T hi/lo bf16 [N][256] -----
__global__ __launch_bounds__(256) void prep_weight(
    const float* __restrict__ W, unsigned short* __restrict__ hi,
    unsigned short* __restrict__ lo, int N, int total)
{
    const int id = blockIdx.x * 256 + threadIdx.x;
    if (id >= total) return;
    const int n = id >> 8;          // 0..N-1
    const int k = id & 255;         // 0..255
    const float f = W[(size_t)k * N + n];
    const unsigned short h = f2bf(f);
    const unsigned short l = f2bf(f - bf2f(h));
    hi[(size_t)n * 256 + k] = h;
    lo[(size_t)n * 256 + k] = l;
}

// ---------------- split-bf16 MFMA GEMM: C = A(Mx256)@B(256xN)+bias(+res) ---
// Tile 128x64, 4 waves (2x2), each wave 64x32 (4x2 frags of 16x16x32).
// LDS double-buffered; one barrier per K-stage (load-early / write-late).
__global__ __launch_bounds__(256) void gemm_mfma_split(
    const float* __restrict__ A,              // M x 256 fp32
    const unsigned short* __restrict__ Bth,   // N x 256 bf16 hi (B^T)
    const unsigned short* __restrict__ Btl,   // N x 256 bf16 lo
    const float* __restrict__ bias,           // N
    const float* __restrict__ res,            // M x N or nullptr
    float* __restrict__ C,                    // M x N
    int M, int N)
{
    __shared__ __align__(16) unsigned short As_hi[2][128][32];
    __shared__ __align__(16) unsigned short As_lo[2][128][32];
    __shared__ __align__(16) unsigned short Bs_hi[2][64][32];
    __shared__ __align__(16) unsigned short Bs_lo[2][64][32];

    const int tid  = threadIdx.x;
    const int wave = tid >> 6, lane = tid & 63;
    const int l15  = lane & 15, kg = lane >> 4;      // kg = 0..3
    const int row0 = blockIdx.x * 128;
    const int col0 = blockIdx.y * 64;
    const int wr   = (wave >> 1) * 64;               // wave row offset
    const int wc   = (wave & 1) * 32;                // wave col offset
    const int arow = tid >> 1, ak = (tid & 1) * 16;  // A staging coords
    const int brow = tid >> 2, bk = (tid & 3) * 8;   // B staging coords

    float4   aR[4];
    bf16x8_t bRh, bRl;

    auto stage_load = [&](int k0) {
        const int r = row0 + arow;
        if (r < M) {
            const float4* ap = (const float4*)&A[(size_t)r * 256 + k0 + ak];
            aR[0] = ap[0]; aR[1] = ap[1]; aR[2] = ap[2]; aR[3] = ap[3];
        } else {
            aR[0] = aR[1] = aR[2] = aR[3] = make_float4(0.f, 0.f, 0.f, 0.f);
        }
        const size_t bb = (size_t)(col0 + brow) * 256 + k0 + bk;
        bRh = *(const bf16x8_t*)&Bth[bb];
        bRl = *(const bf16x8_t*)&Btl[bb];
    };

    auto stage_write = [&](int buf) {
        float t[16];
        *(float4*)&t[0]  = aR[0]; *(float4*)&t[4]  = aR[1];
        *(float4*)&t[8]  = aR[2]; *(float4*)&t[12] = aR[3];
        bf16x8_t h0, l0, h1, l1;
        #pragma unroll
        for (int i = 0; i < 8; ++i) {
            unsigned short h = f2bf(t[i]);
            h0[i] = (short)h; l0[i] = (short)f2bf(t[i] - bf2f(h));
        }
        #pragma unroll
        for (int i = 0; i < 8; ++i) {
            unsigned short h = f2bf(t[8 + i]);
            h1[i] = (short)h; l1[i] = (short)f2bf(t[8 + i] - bf2f(h));
        }
        *(bf16x8_t*)&As_hi[buf][arow][ak]     = h0;
        *(bf16x8_t*)&As_hi[buf][arow][ak + 8] = h1;
        *(bf16x8_t*)&As_lo[buf][arow][ak]     = l0;
        *(bf16x8_t*)&As_lo[buf][arow][ak + 8] = l1;
        *(bf16x8_t*)&Bs_hi[buf][brow][bk] = bRh;
        *(bf16x8_t*)&Bs_lo[buf][brow][bk] = bRl;
    };

    f32x4_t acc[4][2];
    #pragma unroll
    for (int i = 0; i < 4; ++i)
        #pragma unroll
        for (int j = 0; j < 2; ++j)
            acc[i][j] = (f32x4_t){0.f, 0.f, 0.f, 0.f};

    stage_load(0);
    stage_write(0);
    __syncthreads();

    for (int s = 0; s < 8; ++s) {
        const int buf = s & 1;
        if (s < 7) stage_load((s + 1) * 32);

        bf16x8_t ah[4], al[4], bh[2], bl[2];
        #pragma unroll
        for (int mi = 0; mi < 4; ++mi) {
            ah[mi] = *(const bf16x8_t*)&As_hi[buf][wr + mi * 16 + l15][kg * 8];
            al[mi] = *(const bf16x8_t*)&As_lo[buf][wr + mi * 16 + l15][kg * 8];
        }
        #pragma unroll
        for (int nj = 0; nj < 2; ++nj) {
            bh[nj] = *(const bf16x8_t*)&Bs_hi[buf][wc + nj * 16 + l15][kg * 8];
            bl[nj] = *(const bf16x8_t*)&Bs_lo[buf][wc + nj * 16 + l15][kg * 8];
        }
        #pragma unroll
        for (int mi = 0; mi < 4; ++mi)
            #pragma unroll
            for (int nj = 0; nj < 2; ++nj) {
                acc[mi][nj] = __builtin_amdgcn_mfma_f32_16x16x32_bf16(
                    ah[mi], bh[nj], acc[mi][nj], 0, 0, 0);
                acc[mi][nj] = __builtin_amdgcn_mfma_f32_16x16x32_bf16(
                    ah[mi], bl[nj], acc[mi][nj], 0, 0, 0);
                acc[mi][nj] = __builtin_amdgcn_mfma_f32_16x16x32_bf16(
                    al[mi], bh[nj], acc[mi][nj], 0, 0, 0);
            }

        if (s < 7) stage_write(buf ^ 1);
        __syncthreads();
    }

    // epilogue: C/D layout col = lane&15, row = (lane>>4)*4 + reg  [m89]
    #pragma unroll
    for (int nj = 0; nj < 2; ++nj) {
        const int c  = col0 + wc + nj * 16 + l15;
        const float bi = bias[c];
        #pragma unroll
        for (int mi = 0; mi < 4; ++mi) {
            const int rb = row0 + wr + mi * 16 + kg * 4;
            #pragma unroll
            for (int j = 0; j < 4; ++j) {
                const int r = rb + j;
                if (r < M) {
                    float o = acc[mi][nj][j] + bi;
                    if (res) o += res[(size_t)r * N + c];
                    C[(size_t)r * N + c] = o;
                }
            }
        }
    }
}

// ---------------- MSDA sampling: two-phase -------------------------------
// Phase 1 (128 thr): per (head,point) softmax via 16-lane shfl + bilinear
// weights/offsets computed ONCE, folded with validity -> LDS.
// Phase 2 (256 thr): branch-free gather+fma, 32 lanes = 32 channels = one
// 128B line per corner.
__global__ __launch_bounds__(256) void msda_sample_kernel(
    const float* __restrict__ v,       // [BS][NQ][HEADS][HD]
    const float* __restrict__ offs,    // [BS][NQ][HEADS][LEVELS][POINTS][2]
    const float* __restrict__ logits,  // [BS][NQ][HEADS][16]
    const float* __restrict__ refp,    // [BS][NQ][LEVELS][2]
    float* __restrict__ out)           // [BS][NQ][HEADS][HD]
{
    // bijective chunked XCD swizzle (m204): consecutive logical bq -> same XCD
    const int orig = blockIdx.x;
    const int NWG = MROWS;               // 22506
    const int NX = 8, Q = NWG / NX, R = NWG % NX;   // Q=2813, R=2
    const int xcd = orig & 7, lid = orig >> 3;
    const int bq = (xcd < R ? xcd * (Q + 1) : R * (Q + 1) + (xcd - R) * Q) + lid;

    const int tid = threadIdx.x;

    __shared__ float s_off[HEADS * LEVELS * POINTS * 2]; // 256
    __shared__ float s_log[HEADS * LEVELS * POINTS];     // 128
    __shared__ float s_ref[LEVELS * 2];                  // 8
    __shared__ __align__(16) float s_w[HEADS * 16 * 4];  // 512 combined weights
    __shared__ __align__(16) int   s_o[HEADS * 16 * 4];  // 512 element offsets

    const size_t base = (size_t)bq;
    s_off[tid] = offs[base * 256 + tid];
    if (tid < 128) s_log[tid] = logits[base * 128 + tid];
    if (tid < 8)   s_ref[tid] = refp[base * 8 + tid];
    __syncthreads();

    if (tid < 128) {
        const int h = tid >> 4;          // head
        const int p = tid & 15;          // lvl*4 + pt
        const int lvl = p >> 2;

        // softmax over the 16-lane group
        const float logit = s_log[tid];
        float mx = logit;
        #pragma unroll
        for (int m = 1; m < 16; m <<= 1) mx = fmaxf(mx, __shfl_xor(mx, m, 16));
        const float e = expf(logit - mx);
        float sum = e;
        #pragma unroll
        for (int m = 1; m < 16; m <<= 1) sum += __shfl_xor(sum, m, 16);
        const float w = e / sum;

        const int   Wd = (lvl == 0) ? 92 : (lvl == 1) ? 46 : (lvl == 2) ? 23 : 12;
        const int   s0 = (lvl == 0) ? 0  : (lvl == 1) ? 8464 : (lvl == 2) ? 10580 : 11109;
        const float Wf = (float)Wd;

        const float x = s_ref[lvl * 2 + 0] * Wf + s_off[tid * 2 + 0] - 0.5f;
        const float y = s_ref[lvl * 2 + 1] * Wf + s_off[tid * 2 + 1] - 0.5f;
        const float x0f = floorf(x), y0f = floorf(y);
        const int   x0 = (int)x0f,  y0 = (int)y0f;
        const float wx1 = x - x0f, wy1 = y - y0f;
        const float wx0 = 1.f - wx1, wy0 = 1.f - wy1;

        const bool vx0 = (x0 >= 0) & (x0 < Wd);
        const bool vx1 = (x0 >= -1) & (x0 < Wd - 1);
        const bool vy0 = (y0 >= 0) & (y0 < Wd);
        const bool vy1 = (y0 >= -1) & (y0 < Wd - 1);

        const int xc0 = min(max(x0, 0), Wd - 1);
        const int xc1 = min(max(x0 + 1, 0), Wd - 1);
        const int yc0 = min(max(y0, 0), Wd - 1);
        const int yc1 = min(max(y0 + 1, 0), Wd - 1);

        const int hb = h * HD;
        const int r0 = (s0 + yc0 * Wd) * ED + hb;
        const int r1 = (s0 + yc1 * Wd) * ED + hb;

        const int o4 = tid * 4;
        s_w[o4 + 0] = (vx0 & vy0) ? w * wx0 * wy0 : 0.f;
        s_w[o4 + 1] = (vx1 & vy0) ? w * wx1 * wy0 : 0.f;
        s_w[o4 + 2] = (vx0 & vy1) ? w * wx0 * wy1 : 0.f;
        s_w[o4 + 3] = (vx1 & vy1) ? w * wx1 * wy1 : 0.f;
        s_o[o4 + 0] = r0 + xc0 * ED;
        s_o[o4 + 1] = r0 + xc1 * ED;
        s_o[o4 + 2] = r1 + xc0 * ED;
        s_o[o4 + 3] = r1 + xc1 * ED;
    }
    __syncthreads();

    const int h = tid >> 5;              // head
    const int c = tid & 31;              // channel within head
    const int b = bq / NQ;
    const float* __restrict__ vb = v + (size_t)b * NQ * ED + c;

    float acc = 0.f;
    #pragma unroll
    for (int p = 0; p < 16; ++p) {
        const int base4 = (h * 16 + p) * 4;
        const float4 w4 = *(const float4*)&s_w[base4];
        const int4   o4 = *(const int4*)&s_o[base4];
        acc = fmaf(w4.x, vb[o4.x], acc);
        acc = fmaf(w4.y, vb[o4.y], acc);
        acc = fmaf(w4.z, vb[o4.z], acc);
        acc = fmaf(w4.w, vb[o4.w], acc);
    }
    out[base * ED + tid] = acc;
}

// ---------------------------------------------------------------------------
extern "C" void kernel_launch(void* const* d_in, const int* in_sizes, int n_in,
                              void* d_out, int out_size, void* d_ws, size_t ws_size,
                              hipStream_t stream) {
    const float* query = (const float*)d_in[0];   // [BS][NQ][ED]
    const float* value = (const float*)d_in[1];   // [BS][NQ][ED]
    const float* refp  = (const float*)d_in[2];   // [BS][NQ][LEVELS][2]
    // d_in[3] = spatial_shapes (constants, hardcoded)
    const float* W_val  = (const float*)d_in[4];
    const float* b_val  = (const float*)d_in[5];
    const float* W_off  = (const float*)d_in[6];
    const float* b_off  = (const float*)d_in[7];
    const float* W_attn = (const float*)d_in[8];
    const float* b_attn = (const float*)d_in[9];
    const float* W_out  = (const float*)d_in[10];
    const float* b_out  = (const float*)d_in[11];
    float* out = (float*)d_out;

    // workspace carve-up
    float* ws      = (float*)d_ws;
    float* v_ws    = ws;                                   // MROWS*256 f32
    float* off_ws  = v_ws   + (size_t)MROWS * 256;         // MROWS*256
    float* attn_ws = off_ws + (size_t)MROWS * 256;         // MROWS*128
    float* msda_ws = attn_ws + (size_t)MROWS * 128;        // MROWS*256
    unsigned short* wsu = (unsigned short*)(msda_ws + (size_t)MROWS * 256);
    unsigned short* wv_hi = wsu;                  // 65536 each
    unsigned short* wv_lo = wv_hi + 65536;
    unsigned short* wo_hi = wv_lo + 65536;
    unsigned short* wo_lo = wo_hi + 65536;
    unsigned short* wa_hi = wo_lo + 65536;        // 32768 each
    unsigned short* wa_lo = wa_hi + 32768;
    unsigned short* wu_hi = wa_lo + 32768;
    unsigned short* wu_lo = wu_hi + 65536;

    dim3 blk(256);

    // 0. weight transpose + bf16 hi/lo split
    hipLaunchKernelGGL(prep_weight, dim3(65536 / 256), blk, 0, stream,
                       W_val, wv_hi, wv_lo, 256, 65536);
    hipLaunchKernelGGL(prep_weight, dim3(65536 / 256), blk, 0, stream,
                       W_off, wo_hi, wo_lo, 256, 65536);
    hipLaunchKernelGGL(prep_weight, dim3(32768 / 256), blk, 0, stream,
                       W_attn, wa_hi, wa_lo, 128, 32768);
    hipLaunchKernelGGL(prep_weight, dim3(65536 / 256), blk, 0, stream,
                       W_out, wu_hi, wu_lo, 256, 65536);

    const int MB = (MROWS + 127) / 128;   // 176
    // 1. v = value @ W_val + b_val
    hipLaunchKernelGGL(gemm_mfma_split, dim3(MB, 4), blk, 0, stream,
                       value, wv_hi, wv_lo, b_val, nullptr, v_ws, MROWS, 256);
    // 2. offsets = query @ W_off + b_off
    hipLaunchKernelGGL(gemm_mfma_split, dim3(MB, 4), blk, 0, stream,
                       query, wo_hi, wo_lo, b_off, nullptr, off_ws, MROWS, 256);
    // 3. attn logits = query @ W_attn + b_attn
    hipLaunchKernelGGL(gemm_mfma_split, dim3(MB, 2), blk, 0, stream,
                       query, wa_hi, wa_lo, b_attn, nullptr, attn_ws, MROWS, 128);
    // 4. softmax + bilinear sampling + attention-weighted sum
    hipLaunchKernelGGL(msda_sample_kernel, dim3(MROWS), blk, 0, stream,
                       v_ws, off_ws, attn_ws, refp, msda_ws);
    // 5. out = msda @ W_out + b_out + query (residual)
    hipLaunchKernelGGL(gemm_mfma_split, dim3(MB, 4), blk, 0, stream,
                       msda_ws, wu_hi, wu_lo, b_out, query, out, MROWS, 256);
}

// Round 9
// 263.167 us; speedup vs baseline: 1.8518x; 1.4247x over previous
//
#include <hip/hip_runtime.h>
#include <hip/hip_bf16.h>
#include <math.h>

// ---------------- problem constants (fixed by setup_inputs) ----------------
#define BS      2
#define NQ      11253           // 92*92 + 46*46 + 23*23 + 12*12
#define MROWS   (BS * NQ)       // 22506
#define ED      256
#define HEADS   8
#define HD      32
#define LEVELS  4
#define POINTS  4
#define QPB     4               // queries per sampler block

typedef __attribute__((ext_vector_type(8))) short  bf16x8_t;
typedef __attribute__((ext_vector_type(4))) float  f32x4_t;

__device__ __forceinline__ unsigned short f2bf(float f) {
    unsigned int u = __float_as_uint(f);
    u += 0x7FFFu + ((u >> 16) & 1u);          // round-to-nearest-even
    return (unsigned short)(u >> 16);
}
__device__ __forceinline__ float bf2f(unsigned short h) {
    return __uint_as_float(((unsigned int)h) << 16);
}

// ---------------- weight prep: W[K][N] fp32 -> W^T hi/lo bf16 [N][256] -----
__global__ __launch_bounds__(256) void prep_weight(
    const float* __restrict__ W, unsigned short* __restrict__ hi,
    unsigned short* __restrict__ lo, int N, int total)
{
    const int id = blockIdx.x * 256 + threadIdx.x;
    if (id >= total) return;
    const int n = id >> 8;          // 0..N-1
    const int k = id & 255;         // 0..255
    const float f = W[(size_t)k * N + n];
    const unsigned short h = f2bf(f);
    const unsigned short l = f2bf(f - bf2f(h));
    hi[(size_t)n * 256 + k] = h;
    lo[(size_t)n * 256 + k] = l;
}

// ---------------- split-bf16 MFMA GEMM: C = A(Mx256)@B(256xN)+bias(+res) ---
// Tile 128x64, 4 waves (2x2), each wave 64x32 (4x2 frags of 16x16x32).
// Grid: blockIdx.x = column tile (fastest) so same-A-panel blocks co-run
// and share the A fetch via L2. Double-buffered LDS, 1 barrier/K-stage.
__global__ __launch_bounds__(256) void gemm_mfma_split(
    const float* __restrict__ A,              // M x 256 fp32
    const unsigned short* __restrict__ Bth,   // N x 256 bf16 hi (B^T)
    const unsigned short* __restrict__ Btl,   // N x 256 bf16 lo
    const float* __restrict__ bias,           // first nsplit cols
    const float* __restrict__ bias2,          // cols >= nsplit (or null)
    const float* __restrict__ res,            // M x N or nullptr
    float* __restrict__ C,                    // M x N
    int M, int N, int nsplit)
{
    __shared__ __align__(16) unsigned short As_hi[2][128][32];
    __shared__ __align__(16) unsigned short As_lo[2][128][32];
    __shared__ __align__(16) unsigned short Bs_hi[2][64][32];
    __shared__ __align__(16) unsigned short Bs_lo[2][64][32];

    const int tid  = threadIdx.x;
    const int wave = tid >> 6, lane = tid & 63;
    const int l15  = lane & 15, kg = lane >> 4;      // kg = 0..3
    const int row0 = blockIdx.y * 128;
    const int col0 = blockIdx.x * 64;
    const int wr   = (wave >> 1) * 64;               // wave row offset
    const int wc   = (wave & 1) * 32;                // wave col offset
    const int arow = tid >> 1, ak = (tid & 1) * 16;  // A staging coords
    const int brow = tid >> 2, bk = (tid & 3) * 8;   // B staging coords

    float4   aR[4];
    bf16x8_t bRh, bRl;

    auto stage_load = [&](int k0) {
        const int r = row0 + arow;
        if (r < M) {
            const float4* ap = (const float4*)&A[(size_t)r * 256 + k0 + ak];
            aR[0] = ap[0]; aR[1] = ap[1]; aR[2] = ap[2]; aR[3] = ap[3];
        } else {
            aR[0] = aR[1] = aR[2] = aR[3] = make_float4(0.f, 0.f, 0.f, 0.f);
        }
        const size_t bb = (size_t)(col0 + brow) * 256 + k0 + bk;
        bRh = *(const bf16x8_t*)&Bth[bb];
        bRl = *(const bf16x8_t*)&Btl[bb];
    };

    auto stage_write = [&](int buf) {
        float t[16];
        *(float4*)&t[0]  = aR[0]; *(float4*)&t[4]  = aR[1];
        *(float4*)&t[8]  = aR[2]; *(float4*)&t[12] = aR[3];
        bf16x8_t h0, l0, h1, l1;
        #pragma unroll
        for (int i = 0; i < 8; ++i) {
            unsigned short h = f2bf(t[i]);
            h0[i] = (short)h; l0[i] = (short)f2bf(t[i] - bf2f(h));
        }
        #pragma unroll
        for (int i = 0; i < 8; ++i) {
            unsigned short h = f2bf(t[8 + i]);
            h1[i] = (short)h; l1[i] = (short)f2bf(t[8 + i] - bf2f(h));
        }
        *(bf16x8_t*)&As_hi[buf][arow][ak]     = h0;
        *(bf16x8_t*)&As_hi[buf][arow][ak + 8] = h1;
        *(bf16x8_t*)&As_lo[buf][arow][ak]     = l0;
        *(bf16x8_t*)&As_lo[buf][arow][ak + 8] = l1;
        *(bf16x8_t*)&Bs_hi[buf][brow][bk] = bRh;
        *(bf16x8_t*)&Bs_lo[buf][brow][bk] = bRl;
    };

    f32x4_t acc[4][2];
    #pragma unroll
    for (int i = 0; i < 4; ++i)
        #pragma unroll
        for (int j = 0; j < 2; ++j)
            acc[i][j] = (f32x4_t){0.f, 0.f, 0.f, 0.f};

    stage_load(0);
    stage_write(0);
    __syncthreads();

    for (int s = 0; s < 8; ++s) {
        const int buf = s & 1;
        if (s < 7) stage_load((s + 1) * 32);

        bf16x8_t ah[4], al[4], bh[2], bl[2];
        #pragma unroll
        for (int mi = 0; mi < 4; ++mi) {
            ah[mi] = *(const bf16x8_t*)&As_hi[buf][wr + mi * 16 + l15][kg * 8];
            al[mi] = *(const bf16x8_t*)&As_lo[buf][wr + mi * 16 + l15][kg * 8];
        }
        #pragma unroll
        for (int nj = 0; nj < 2; ++nj) {
            bh[nj] = *(const bf16x8_t*)&Bs_hi[buf][wc + nj * 16 + l15][kg * 8];
            bl[nj] = *(const bf16x8_t*)&Bs_lo[buf][wc + nj * 16 + l15][kg * 8];
        }
        #pragma unroll
        for (int mi = 0; mi < 4; ++mi)
            #pragma unroll
            for (int nj = 0; nj < 2; ++nj) {
                acc[mi][nj] = __builtin_amdgcn_mfma_f32_16x16x32_bf16(
                    ah[mi], bh[nj], acc[mi][nj], 0, 0, 0);
                acc[mi][nj] = __builtin_amdgcn_mfma_f32_16x16x32_bf16(
                    ah[mi], bl[nj], acc[mi][nj], 0, 0, 0);
                acc[mi][nj] = __builtin_amdgcn_mfma_f32_16x16x32_bf16(
                    al[mi], bh[nj], acc[mi][nj], 0, 0, 0);
            }

        if (s < 7) stage_write(buf ^ 1);
        __syncthreads();
    }

    // epilogue: C/D layout col = lane&15, row = (lane>>4)*4 + reg  [m89]
    #pragma unroll
    for (int nj = 0; nj < 2; ++nj) {
        const int c = col0 + wc + nj * 16 + l15;
        const float bi = (c < nsplit) ? bias[c] : bias2[c - nsplit];
        #pragma unroll
        for (int mi = 0; mi < 4; ++mi) {
            const int rb = row0 + wr + mi * 16 + kg * 4;
            #pragma unroll
            for (int j = 0; j < 4; ++j) {
                const int r = rb + j;
                if (r < M) {
                    float o = acc[mi][nj][j] + bi;
                    if (res) o += res[(size_t)r * N + c];
                    C[(size_t)r * N + c] = o;
                }
            }
        }
    }
}

// ---------------- MSDA sampling: two-phase, 4 queries/block ----------------
// Phase 1 (all 256 thr, 2 units each): per (q,head,point) softmax via
// 16-lane shfl + bilinear weights/offsets folded with validity -> LDS.
// Phase 2: one wave per query; 8 lanes x float4 = 128B line per head;
// 2 points (8 float4 gathers) in flight per iteration.
__global__ __launch_bounds__(256) void msda_sample_kernel(
    const float* __restrict__ v,       // [BS][NQ][HEADS][HD]
    const float* __restrict__ cat,     // [M][384]: 256 offs | 128 logits
    const float* __restrict__ refp,    // [BS][NQ][LEVELS][2]
    float* __restrict__ out)           // [M][HEADS][HD]
{
    const int q0  = blockIdx.x * QPB;
    const int tid = threadIdx.x;

    __shared__ float s_in[QPB][384];                     // offs+logits
    __shared__ float s_ref[QPB][8];
    __shared__ __align__(16) float s_w[QPB][16][HEADS][4];
    __shared__ __align__(16) int   s_o[QPB][16][HEADS][4];

    for (int i = tid; i < QPB * 384; i += 256) {
        const int q = i / 384, j = i - q * 384;
        const int qq = q0 + q;
        s_in[q][j] = (qq < MROWS) ? cat[(size_t)qq * 384 + j] : 0.f;
    }
    if (tid < QPB * 8) {
        const int q = tid >> 3, j = tid & 7;
        const int qq = q0 + q;
        s_ref[q][j] = (qq < MROWS) ? refp[(size_t)qq * 8 + j] : 0.5f;
    }
    __syncthreads();

    #pragma unroll
    for (int rep = 0; rep < 2; ++rep) {
        const int u  = rep * 256 + tid;      // 0..511
        const int p  = u & 15;               // lvl*4 + pt
        const int gh = u >> 4;               // q*8 + h
        const int q  = gh >> 3, h = gh & 7;
        const int lvl = p >> 2;

        // softmax over the 16-lane group (lanes of a group share (q,h))
        const float logit = s_in[q][256 + h * 16 + p];
        float mx = logit;
        #pragma unroll
        for (int m = 1; m < 16; m <<= 1) mx = fmaxf(mx, __shfl_xor(mx, m, 16));
        const float e = __expf(logit - mx);
        float sum = e;
        #pragma unroll
        for (int m = 1; m < 16; m <<= 1) sum += __shfl_xor(sum, m, 16);
        const float w = e / sum;

        const int   Wd = (lvl == 0) ? 92 : (lvl == 1) ? 46 : (lvl == 2) ? 23 : 12;
        const int   s0 = (lvl == 0) ? 0  : (lvl == 1) ? 8464 : (lvl == 2) ? 10580 : 11109;
        const float Wf = (float)Wd;

        const float x = s_ref[q][lvl * 2 + 0] * Wf + s_in[q][h * 32 + p * 2 + 0] - 0.5f;
        const float y = s_ref[q][lvl * 2 + 1] * Wf + s_in[q][h * 32 + p * 2 + 1] - 0.5f;
        const float x0f = floorf(x), y0f = floorf(y);
        const int   x0 = (int)x0f,  y0 = (int)y0f;
        const float wx1 = x - x0f, wy1 = y - y0f;
        const float wx0 = 1.f - wx1, wy0 = 1.f - wy1;

        const bool vx0 = (x0 >= 0) & (x0 < Wd);
        const bool vx1 = (x0 >= -1) & (x0 < Wd - 1);
        const bool vy0 = (y0 >= 0) & (y0 < Wd);
        const bool vy1 = (y0 >= -1) & (y0 < Wd - 1);

        const int xc0 = min(max(x0, 0), Wd - 1);
        const int xc1 = min(max(x0 + 1, 0), Wd - 1);
        const int yc0 = min(max(y0, 0), Wd - 1);
        const int yc1 = min(max(y0 + 1, 0), Wd - 1);

        const int hb = h * HD;
        const int r0 = (s0 + yc0 * Wd) * ED + hb;
        const int r1 = (s0 + yc1 * Wd) * ED + hb;

        s_w[q][p][h][0] = (vx0 & vy0) ? w * wx0 * wy0 : 0.f;
        s_w[q][p][h][1] = (vx1 & vy0) ? w * wx1 * wy0 : 0.f;
        s_w[q][p][h][2] = (vx0 & vy1) ? w * wx0 * wy1 : 0.f;
        s_w[q][p][h][3] = (vx1 & vy1) ? w * wx1 * wy1 : 0.f;
        s_o[q][p][h][0] = r0 + xc0 * ED;
        s_o[q][p][h][1] = r0 + xc1 * ED;
        s_o[q][p][h][2] = r1 + xc0 * ED;
        s_o[q][p][h][3] = r1 + xc1 * ED;
    }
    __syncthreads();

    // phase 2: wave = one query; lane l: h = l>>3, 4 channels (l&7)*4
    const int q  = tid >> 6, l = tid & 63;
    const int h  = l >> 3,  c4 = (l & 7) * 4;
    const int qq = q0 + q;
    const int qc = (qq < MROWS) ? qq : MROWS - 1;
    const int b  = qc / NQ;
    const float* __restrict__ vb = v + (size_t)b * NQ * ED + c4;

    float4 acc = make_float4(0.f, 0.f, 0.f, 0.f);
    #pragma unroll
    for (int p = 0; p < 16; p += 2) {
        const float4 wA = *(const float4*)&s_w[q][p][h][0];
        const int4   oA = *(const int4*)&s_o[q][p][h][0];
        const float4 wB = *(const float4*)&s_w[q][p + 1][h][0];
        const int4   oB = *(const int4*)&s_o[q][p + 1][h][0];
        const float4 a0 = *(const float4*)&vb[oA.x];
        const float4 a1 = *(const float4*)&vb[oA.y];
        const float4 a2 = *(const float4*)&vb[oA.z];
        const float4 a3 = *(const float4*)&vb[oA.w];
        const float4 b0 = *(const float4*)&vb[oB.x];
        const float4 b1 = *(const float4*)&vb[oB.y];
        const float4 b2 = *(const float4*)&vb[oB.z];
        const float4 b3 = *(const float4*)&vb[oB.w];
        acc.x = fmaf(wA.x, a0.x, acc.x); acc.y = fmaf(wA.x, a0.y, acc.y);
        acc.z = fmaf(wA.x, a0.z, acc.z); acc.w = fmaf(wA.x, a0.w, acc.w);
        acc.x = fmaf(wA.y, a1.x, acc.x); acc.y = fmaf(wA.y, a1.y, acc.y);
        acc.z = fmaf(wA.y, a1.z, acc.z); acc.w = fmaf(wA.y, a1.w, acc.w);
        acc.x = fmaf(wA.z, a2.x, acc.x); acc.y = fmaf(wA.z, a2.y, acc.y);
        acc.z = fmaf(wA.z, a2.z, acc.z); acc.w = fmaf(wA.z, a2.w, acc.w);
        acc.x = fmaf(wA.w, a3.x, acc.x); acc.y = fmaf(wA.w, a3.y, acc.y);
        acc.z = fmaf(wA.w, a3.z, acc.z); acc.w = fmaf(wA.w, a3.w, acc.w);
        acc.x = fmaf(wB.x, b0.x, acc.x); acc.y = fmaf(wB.x, b0.y, acc.y);
        acc.z = fmaf(wB.x, b0.z, acc.z); acc.w = fmaf(wB.x, b0.w, acc.w);
        acc.x = fmaf(wB.y, b1.x, acc.x); acc.y = fmaf(wB.y, b1.y, acc.y);
        acc.z = fmaf(wB.y, b1.z, acc.z); acc.w = fmaf(wB.y, b1.w, acc.w);
        acc.x = fmaf(wB.z, b2.x, acc.x); acc.y = fmaf(wB.z, b2.y, acc.y);
        acc.z = fmaf(wB.z, b2.z, acc.z); acc.w = fmaf(wB.z, b2.w, acc.w);
        acc.x = fmaf(wB.w, b3.x, acc.x); acc.y = fmaf(wB.w, b3.y, acc.y);
        acc.z = fmaf(wB.w, b3.z, acc.z); acc.w = fmaf(wB.w, b3.w, acc.w);
    }
    if (qq < MROWS)
        *(float4*)&out[(size_t)qq * ED + h * HD + c4] = acc;
}

// ---------------------------------------------------------------------------
extern "C" void kernel_launch(void* const* d_in, const int* in_sizes, int n_in,
                              void* d_out, int out_size, void* d_ws, size_t ws_size,
                              hipStream_t stream) {
    const float* query = (const float*)d_in[0];   // [BS][NQ][ED]
    const float* value = (const float*)d_in[1];   // [BS][NQ][ED]
    const float* refp  = (const float*)d_in[2];   // [BS][NQ][LEVELS][2]
    // d_in[3] = spatial_shapes (constants, hardcoded)
    const float* W_val  = (const float*)d_in[4];
    const float* b_val  = (const float*)d_in[5];
    const float* W_off  = (const float*)d_in[6];
    const float* b_off  = (const float*)d_in[7];
    const float* W_attn = (const float*)d_in[8];
    const float* b_attn = (const float*)d_in[9];
    const float* W_out  = (const float*)d_in[10];
    const float* b_out  = (const float*)d_in[11];
    float* out = (float*)d_out;

    // workspace carve-up (total cols/row: 256+384+256 = 896)
    float* ws      = (float*)d_ws;
    float* v_ws    = ws;                                   // M*256 f32
    float* cat_ws  = v_ws   + (size_t)MROWS * 256;         // M*384
    float* msda_ws = cat_ws + (size_t)MROWS * 384;         // M*256
    unsigned short* wsu = (unsigned short*)(msda_ws + (size_t)MROWS * 256);
    unsigned short* wv_hi = wsu;                  // 65536
    unsigned short* wv_lo = wv_hi + 65536;
    unsigned short* wc_hi = wv_lo + 65536;        // 98304 (384 rows x 256)
    unsigned short* wc_lo = wc_hi + 98304;
    unsigned short* wu_hi = wc_lo + 98304;        // 65536
    unsigned short* wu_lo = wu_hi + 65536;

    dim3 blk(256);

    // 0. weight transpose + bf16 hi/lo split (attn lands at rows 256..383)
    hipLaunchKernelGGL(prep_weight, dim3(256), blk, 0, stream,
                       W_val, wv_hi, wv_lo, 256, 65536);
    hipLaunchKernelGGL(prep_weight, dim3(256), blk, 0, stream,
                       W_off, wc_hi, wc_lo, 256, 65536);
    hipLaunchKernelGGL(prep_weight, dim3(128), blk, 0, stream,
                       W_attn, wc_hi + 65536, wc_lo + 65536, 128, 32768);
    hipLaunchKernelGGL(prep_weight, dim3(256), blk, 0, stream,
                       W_out, wu_hi, wu_lo, 256, 65536);

    const int MB = (MROWS + 127) / 128;   // 176
    // 1. v = value @ W_val + b_val
    hipLaunchKernelGGL(gemm_mfma_split, dim3(4, MB), blk, 0, stream,
                       value, wv_hi, wv_lo, b_val, (const float*)nullptr,
                       (const float*)nullptr, v_ws, MROWS, 256, 256);
    // 2. [offsets | logits] = query @ [W_off | W_attn] + [b_off | b_attn]
    hipLaunchKernelGGL(gemm_mfma_split, dim3(6, MB), blk, 0, stream,
                       query, wc_hi, wc_lo, b_off, b_attn,
                       (const float*)nullptr, cat_ws, MROWS, 384, 256);
    // 3. softmax + bilinear sampling + attention-weighted sum
    hipLaunchKernelGGL(msda_sample_kernel, dim3((MROWS + QPB - 1) / QPB), blk,
                       0, stream, v_ws, cat_ws, refp, msda_ws);
    // 4. out = msda @ W_out + b_out + query (residual)
    hipLaunchKernelGGL(gemm_mfma_split, dim3(4, MB), blk, 0, stream,
                       msda_ws, wu_hi, wu_lo, b_out, (const float*)nullptr,
                       query, out, MROWS, 256, 256);
}